// Round 10
// baseline (2452.484 us; speedup 1.0000x reference)
//
#include <hip/hip_runtime.h>
#include <math.h>

#define BB     4
#define LLEN   409
#define DMODEL 192
#define DINNER 384
#define DSTATE 16
#define DRANK  12
#define KCONV  4
#define NLAYER 24
#define NROW   (BB*LLEN)      /* 1636 */
#define EPSF   1e-5f
#define CH2    16             /* scan chunk length */
#define NCH2   26             /* 16*26=416 >= 409 */

__device__ __forceinline__ float siluf(float x){ return x/(1.f+__expf(-x)); }
__device__ __forceinline__ float softplusf(float x){ return (x>20.f)? x : log1pf(__expf(x)); }

// ---------------- prep kernels ----------------
__global__ void k_init(const float* __restrict__ t, float* __restrict__ r, int n){
  int i = blockIdx.x*256+threadIdx.x;
  if (i<n) r[i]=t[i];
}

// AnT[l][n][d] = -exp(A_log[l][d][n]); output-contiguous writes
__global__ void k_negexpT2(const float* __restrict__ a, float* __restrict__ o, int n){
  int i = blockIdx.x*256+threadIdx.x;
  if (i<n){
    int l = i/(DINNER*DSTATE); int rem = i%(DINNER*DSTATE);
    int nn = rem/DINNER, d = rem%DINNER;
    o[i] = -expf(a[((size_t)l*DINNER + d)*DSTATE + nn]);
  }
}

// ---------------- layer kernels ----------------
// RMSNorm: xn = residual * rsqrt(mean sq) * norm_w; one wave per row
__global__ __launch_bounds__(256) void k_prenorm(const float* __restrict__ residual,
    const float* __restrict__ norm_w, float* __restrict__ xn){
  int wv = threadIdx.x>>6, lane = threadIdx.x&63;
  int row = blockIdx.x*4 + wv;
  if (row >= NROW) return;
  float v[3]; float s = 0.f;
  #pragma unroll
  for (int q=0;q<3;q++){ v[q] = residual[(size_t)row*DMODEL + lane + q*64]; s += v[q]*v[q]; }
  #pragma unroll
  for (int off=1; off<64; off<<=1) s += __shfl_xor(s, off, 64);
  float sc = rsqrtf(s/(float)DMODEL + EPSF);
  #pragma unroll
  for (int q=0;q<3;q++) xn[(size_t)row*DMODEL + lane + q*64] = v[q]*sc*norm_w[lane + q*64];
}

// in_proj GEMM (native W [768][192]): xz[row][j] = sum_k xn[row][k]*W[j][k]
// BM=16 BN=64; grid (103,12)
__global__ __launch_bounds__(256) void k_gemm_in(const float* __restrict__ xn,
    const float* __restrict__ W, float* __restrict__ xz){
  __shared__ __align__(16) float w_s[64*193];
  __shared__ __align__(16) float a_lds[192*20];
  int tid = threadIdx.x, r0 = blockIdx.x*16, c0 = blockIdx.y*64;
  // stage 64 native W rows (c0..c0+63), each 192 floats; flat-f mapping, coalesced
  #pragma unroll
  for (int i=0;i<12;i++){
    int f = i*256 + tid;              // < 3072 float4 units
    int jj = f/48, p = f%48;
    *reinterpret_cast<float4*>(&w_s[jj*193 + p*4]) =
      *reinterpret_cast<const float4*>(&W[(size_t)(c0+jj)*192 + p*4]);
  }
  // stage A tile [192 k][16 rows], pad 20
  {
    int i = tid>>4, kc = (tid&15)*12;
    int row = r0+i;
    #pragma unroll
    for (int m=0;m<12;m+=4){
      float4 v = make_float4(0.f,0.f,0.f,0.f);
      if (row<NROW) v = *reinterpret_cast<const float4*>(&xn[(size_t)row*192 + kc + m]);
      a_lds[(kc+m+0)*20+i]=v.x; a_lds[(kc+m+1)*20+i]=v.y;
      a_lds[(kc+m+2)*20+i]=v.z; a_lds[(kc+m+3)*20+i]=v.w;
    }
  }
  __syncthreads();
  int j = tid & 63, rg = tid >> 6;
  float acc[4] = {0.f,0.f,0.f,0.f};
  #pragma unroll 8
  for (int k=0;k<192;k++){
    float w = w_s[j*193+k];
    float4 a = *reinterpret_cast<const float4*>(&a_lds[k*20 + rg*4]);
    acc[0]+=a.x*w; acc[1]+=a.y*w; acc[2]+=a.z*w; acc[3]+=a.w*w;
  }
  #pragma unroll
  for (int q=0;q<4;q++){
    int row = r0 + rg*4 + q;
    if (row<NROW) xz[(size_t)row*768 + c0 + j] = acc[q];
  }
}

// causal depthwise conv + bias + silu, float4 over d; grid (614, 2)
__global__ __launch_bounds__(256) void k_conv(const float* __restrict__ xz,
    const float* __restrict__ cwf, const float* __restrict__ cbf,
    const float* __restrict__ cwb, const float* __restrict__ cbb,
    float* __restrict__ xf_f, float* __restrict__ xf_b){
  int idx = blockIdx.x*256 + threadIdx.x;
  if (idx >= NROW*(DINNER/4)) return;
  int d4 = (idx % (DINNER/4))*4; int bl = idx / (DINNER/4);
  int b = bl / LLEN; int l = bl % LLEN;
  int dir = blockIdx.y;
  const float* cw = dir? cwb : cwf;
  const float* cb = dir? cbb : cbf;
  float4 w0 = *reinterpret_cast<const float4*>(&cw[(d4+0)*KCONV]);
  float4 w1 = *reinterpret_cast<const float4*>(&cw[(d4+1)*KCONV]);
  float4 w2 = *reinterpret_cast<const float4*>(&cw[(d4+2)*KCONV]);
  float4 w3 = *reinterpret_cast<const float4*>(&cw[(d4+3)*KCONV]);
  float4 acc = *reinterpret_cast<const float4*>(&cb[d4]);
  const float* wa0 = (const float*)&w0; const float* wa1 = (const float*)&w1;
  const float* wa2 = (const float*)&w2; const float* wa3 = (const float*)&w3;
  #pragma unroll
  for (int k=0;k<KCONV;k++){
    int o = dir? (LLEN-1-l-k+3) : (l-3+k);
    bool ok = dir? (l+k>=3) : (o>=0);
    if (ok){
      float4 x = *reinterpret_cast<const float4*>(&xz[((size_t)(b*LLEN+o))*768 + d4]);
      acc.x += wa0[k]*x.x; acc.y += wa1[k]*x.y; acc.z += wa2[k]*x.z; acc.w += wa3[k]*x.w;
    }
  }
  float* out = dir? xf_b : xf_f;
  float4 r; r.x = siluf(acc.x); r.y = siluf(acc.y); r.z = siluf(acc.z); r.w = siluf(acc.w);
  *reinterpret_cast<float4*>(&out[(size_t)bl*DINNER + d4]) = r;
}

// x_proj (native W [44][384], zero-padded to 64 rows in LDS) + dt_proj (native [384][12])
// BM=16; grid (103,1,2)
__global__ __launch_bounds__(256) void k_xp2(
    const float* __restrict__ xf_f, const float* __restrict__ xf_b,
    const float* __restrict__ WxpF, const float* __restrict__ WxpB,  // [44][384]
    const float* __restrict__ WdtF, const float* __restrict__ WdtB,  // [384][12]
    const float* __restrict__ dtbF, const float* __restrict__ dtbB,
    float* __restrict__ dtbc_f, float* __restrict__ dtbc_b,
    float* __restrict__ dt_f, float* __restrict__ dt_b){
  __shared__ __align__(16) float w_s[64*193];
  __shared__ __align__(16) float a_lds[192*20];
  __shared__ float dtin_s[16*12];
  int dir = blockIdx.z;
  const float* xf  = dir? xf_b : xf_f;
  const float* Wxp = dir? WxpB : WxpF;
  const float* Wdt = dir? WdtB : WdtF;
  const float* dtb = dir? dtbB : dtbF;
  float* dtbc = dir? dtbc_b : dtbc_f;
  float* dtp  = dir? dt_b  : dt_f;
  int tid = threadIdx.x, r0 = blockIdx.x*16;
  int j = tid & 63, rg = tid >> 6;
  float acc[4] = {0.f,0.f,0.f,0.f};
  for (int c=0;c<2;c++){
    int K0 = c*192;
    if (c) __syncthreads();
    // stage W rows (j<44 native, j>=44 zero), K-chunk of 192
    #pragma unroll
    for (int i=0;i<12;i++){
      int f = i*256 + tid;
      int jj = f/48, p = f%48;
      float4 v = make_float4(0.f,0.f,0.f,0.f);
      if (jj<44) v = *reinterpret_cast<const float4*>(&Wxp[(size_t)jj*384 + K0 + p*4]);
      *reinterpret_cast<float4*>(&w_s[jj*193 + p*4]) = v;
    }
    {
      int i = tid>>4, kc = (tid&15)*12;
      int row = r0+i;
      #pragma unroll
      for (int m=0;m<12;m+=4){
        float4 v = make_float4(0.f,0.f,0.f,0.f);
        if (row<NROW) v = *reinterpret_cast<const float4*>(&xf[(size_t)row*DINNER + K0 + kc + m]);
        a_lds[(kc+m+0)*20+i]=v.x; a_lds[(kc+m+1)*20+i]=v.y;
        a_lds[(kc+m+2)*20+i]=v.z; a_lds[(kc+m+3)*20+i]=v.w;
      }
    }
    __syncthreads();
    #pragma unroll 8
    for (int k=0;k<192;k++){
      float w = w_s[j*193+k];
      float4 a = *reinterpret_cast<const float4*>(&a_lds[k*20 + rg*4]);
      acc[0]+=a.x*w; acc[1]+=a.y*w; acc[2]+=a.z*w; acc[3]+=a.w*w;
    }
  }
  __syncthreads();
  #pragma unroll
  for (int q=0;q<4;q++){
    int i = rg*4+q, row = r0+i;
    if (j<44 && row<NROW) dtbc[(size_t)row*44 + j] = acc[q];
    if (j<12) dtin_s[i*12 + j] = acc[q];
  }
  __syncthreads();
  // dt_proj from native Wdt[dd][r] (12 contiguous floats per dd, L2-hot)
  for (int idx=tid; idx<16*DINNER; idx+=256){
    int i = idx/DINNER, dd = idx - i*DINNER;
    int row = r0+i;
    if (row<NROW){
      const float* wr = &Wdt[(size_t)dd*DRANK];
      float v = dtb[dd];
      #pragma unroll
      for (int r=0;r<12;r++) v += dtin_s[i*12+r]*wr[r];
      dtp[(size_t)row*DINNER+dd] = softplusf(v);
    }
  }
}

// scan pass 1: per-chunk transfer fn; thread = one d, 16 n-states in regs
// grid (3, BB*NCH2, 2), 128 threads
__global__ __launch_bounds__(128) void k_scan1(
    const float* __restrict__ xf_f, const float* __restrict__ xf_b,
    const float* __restrict__ dtbc_f, const float* __restrict__ dtbc_b,
    const float* __restrict__ dt_f, const float* __restrict__ dt_b,
    const float* __restrict__ anF, const float* __restrict__ anB,
    float* __restrict__ q_buf, float* __restrict__ sdt_buf){
  int dir = blockIdx.z;
  int b  = blockIdx.y / NCH2;
  int ch = blockIdx.y % NCH2;
  const float* xf   = dir? xf_b  : xf_f;
  const float* dtbc = dir? dtbc_b: dtbc_f;
  const float* dtp  = dir? dt_b  : dt_f;
  const float* an   = dir? anB   : anF;
  int t0 = ch*CH2;
  int T  = (t0+CH2<=LLEN)? CH2 : (LLEN-t0);
  int d0 = blockIdx.x*128;
  size_t base = (size_t)b*LLEN + t0;
  __shared__ float dt_s[CH2*128], u_s[CH2*128];
  __shared__ __align__(16) float B_s[CH2*16];
  int tid = threadIdx.x;
  for (int t=0;t<T;t++){
    dt_s[t*128+tid] = dtp[(base+t)*DINNER + d0 + tid];
    u_s [t*128+tid] = xf [(base+t)*DINNER + d0 + tid];
  }
  for (int idx = tid; idx < T*16; idx += 128){
    int t = idx>>4, n = idx&15;
    B_s[idx] = dtbc[(base+t)*44 + 12 + n];
  }
  __syncthreads();
  int d = d0 + tid;
  float A[16], h[16];
  #pragma unroll
  for (int n=0;n<16;n++){ A[n] = an[n*DINNER + d]; h[n] = 0.f; }
  float sdt = 0.f;
  for (int t=0;t<T;t++){
    float dtv = dt_s[t*128+tid];
    float du  = dtv * u_s[t*128+tid];
    float Bv[16];
    #pragma unroll
    for (int q=0;q<4;q++) *reinterpret_cast<float4*>(&Bv[q*4]) =
        *reinterpret_cast<const float4*>(&B_s[t*16 + q*4]);
    #pragma unroll
    for (int n=0;n<16;n++) h[n] = h[n]*__expf(dtv*A[n]) + du*Bv[n];
    sdt += dtv;
  }
  size_t ci = ((size_t)dir*BB + b)*NCH2 + ch;
  float* qo = &q_buf[(ci*DINNER + d)*DSTATE];
  #pragma unroll
  for (int q=0;q<4;q++) *reinterpret_cast<float4*>(&qo[q*4]) =
      make_float4(h[q*4+0], h[q*4+1], h[q*4+2], h[q*4+3]);
  sdt_buf[ci*DINNER + d] = sdt;
}

// scan pass 2: fold carries of preceding chunks in-thread, replay chunk, emit y
// grid (3, BB*NCH2, 2), 128 threads
__global__ __launch_bounds__(128) void k_scan2(
    const float* __restrict__ xf_f, const float* __restrict__ xf_b,
    const float* __restrict__ dtbc_f, const float* __restrict__ dtbc_b,
    const float* __restrict__ dt_f, const float* __restrict__ dt_b,
    const float* __restrict__ anF, const float* __restrict__ anB,
    const float* __restrict__ DpF, const float* __restrict__ DpB,
    const float* __restrict__ q_buf, const float* __restrict__ sdt_buf,
    float* __restrict__ y_fo, float* __restrict__ y_bo){
  int dir = blockIdx.z;
  int b  = blockIdx.y / NCH2;
  int ch = blockIdx.y % NCH2;
  const float* xf   = dir? xf_b  : xf_f;
  const float* dtbc = dir? dtbc_b: dtbc_f;
  const float* dtp  = dir? dt_b  : dt_f;
  const float* an   = dir? anB   : anF;
  const float* Dp   = dir? DpB   : DpF;
  float* y = dir? y_bo : y_fo;
  int t0 = ch*CH2;
  int T  = (t0+CH2<=LLEN)? CH2 : (LLEN-t0);
  int d0 = blockIdx.x*128;
  size_t base = (size_t)b*LLEN + t0;
  __shared__ float dt_s[CH2*128], u_s[CH2*128];
  __shared__ __align__(16) float B_s[CH2*16], C_s[CH2*16];
  int tid = threadIdx.x;
  for (int t=0;t<T;t++){
    dt_s[t*128+tid] = dtp[(base+t)*DINNER + d0 + tid];
    u_s [t*128+tid] = xf [(base+t)*DINNER + d0 + tid];
  }
  for (int idx = tid; idx < T*16; idx += 128){
    int t = idx>>4, n = idx&15;
    B_s[idx] = dtbc[(base+t)*44 + 12 + n];
    C_s[idx] = dtbc[(base+t)*44 + 28 + n];
  }
  __syncthreads();
  int d = d0 + tid;
  float A[16], h[16];
  #pragma unroll
  for (int n=0;n<16;n++){ A[n] = an[n*DINNER + d]; h[n] = 0.f; }
  // fold transfer functions of preceding chunks: h <- q_cc + exp(A*sdt_cc)*h
  size_t sbase = ((size_t)dir*BB + b)*NCH2;
  for (int cc=0; cc<ch; cc++){
    float sv = sdt_buf[(sbase+cc)*DINNER + d];
    const float* qp = &q_buf[((sbase+cc)*DINNER + d)*DSTATE];
    float qv[16];
    #pragma unroll
    for (int q=0;q<4;q++) *reinterpret_cast<float4*>(&qv[q*4]) =
        *reinterpret_cast<const float4*>(&qp[q*4]);
    #pragma unroll
    for (int n=0;n<16;n++) h[n] = qv[n] + __expf(A[n]*sv)*h[n];
  }
  float Dd = Dp[d];
  for (int t=0;t<T;t++){
    float dtv = dt_s[t*128+tid];
    float u   = u_s [t*128+tid];
    float du  = dtv*u;
    float Bv[16], Cv[16];
    #pragma unroll
    for (int q=0;q<4;q++){
      *reinterpret_cast<float4*>(&Bv[q*4]) = *reinterpret_cast<const float4*>(&B_s[t*16+q*4]);
      *reinterpret_cast<float4*>(&Cv[q*4]) = *reinterpret_cast<const float4*>(&C_s[t*16+q*4]);
    }
    float y0=0.f, y1=0.f, y2=0.f, y3=0.f;
    #pragma unroll
    for (int n=0;n<16;n+=4){
      h[n+0] = h[n+0]*__expf(dtv*A[n+0]) + du*Bv[n+0];
      h[n+1] = h[n+1]*__expf(dtv*A[n+1]) + du*Bv[n+1];
      h[n+2] = h[n+2]*__expf(dtv*A[n+2]) + du*Bv[n+2];
      h[n+3] = h[n+3]*__expf(dtv*A[n+3]) + du*Bv[n+3];
      y0 += h[n+0]*Cv[n+0]; y1 += h[n+1]*Cv[n+1];
      y2 += h[n+2]*Cv[n+2]; y3 += h[n+3]*Cv[n+3];
    }
    y[(base+t)*DINNER + d] = (y0+y1)+(y2+y3) + u*Dd;
  }
}

// gate: g = (y_f + y_b(reversed)) * silu(z) * 0.5; grid (614)
__global__ __launch_bounds__(256) void k_gate(
    const float* __restrict__ y_f, const float* __restrict__ y_b,
    const float* __restrict__ xz, float* __restrict__ g){
  int idx = blockIdx.x*256 + threadIdx.x;
  if (idx >= NROW*(DINNER/4)) return;
  int d4 = (idx % (DINNER/4))*4; int row = idx / (DINNER/4);
  int b = row/LLEN, l = row%LLEN;
  int rrow = b*LLEN + (LLEN-1-l);
  float4 yf = *reinterpret_cast<const float4*>(&y_f[(size_t)row*DINNER + d4]);
  float4 yb = *reinterpret_cast<const float4*>(&y_b[(size_t)rrow*DINNER + d4]);
  float4 z  = *reinterpret_cast<const float4*>(&xz[(size_t)row*768 + DINNER + d4]);
  float4 r;
  r.x = (yf.x+yb.x)*siluf(z.x)*0.5f; r.y = (yf.y+yb.y)*siluf(z.y)*0.5f;
  r.z = (yf.z+yb.z)*siluf(z.z)*0.5f; r.w = (yf.w+yb.w)*siluf(z.w)*0.5f;
  *reinterpret_cast<float4*>(&g[(size_t)row*DINNER + d4]) = r;
}

// out_proj GEMM (native W [192][384]): residual[row][j] += sum_e g[row][e]*W[j][e]
// BM=16 BN=64; grid (103,3)
__global__ __launch_bounds__(256) void k_gemm_out(const float* __restrict__ g,
    const float* __restrict__ W, float* __restrict__ residual){
  __shared__ __align__(16) float w_s[64*193];
  __shared__ __align__(16) float a_lds[192*20];
  int tid = threadIdx.x, r0 = blockIdx.x*16, c0 = blockIdx.y*64;
  int j = tid & 63, rg = tid >> 6;
  float acc[4] = {0.f,0.f,0.f,0.f};
  for (int c=0;c<2;c++){
    int K0 = c*192;
    if (c) __syncthreads();
    #pragma unroll
    for (int i=0;i<12;i++){
      int f = i*256 + tid;
      int jj = f/48, p = f%48;
      *reinterpret_cast<float4*>(&w_s[jj*193 + p*4]) =
        *reinterpret_cast<const float4*>(&W[(size_t)(c0+jj)*384 + K0 + p*4]);
    }
    {
      int i = tid>>4, kc = (tid&15)*12;
      int row = r0+i;
      #pragma unroll
      for (int m=0;m<12;m+=4){
        float4 v = make_float4(0.f,0.f,0.f,0.f);
        if (row<NROW) v = *reinterpret_cast<const float4*>(&g[(size_t)row*DINNER + K0 + kc + m]);
        a_lds[(kc+m+0)*20+i]=v.x; a_lds[(kc+m+1)*20+i]=v.y;
        a_lds[(kc+m+2)*20+i]=v.z; a_lds[(kc+m+3)*20+i]=v.w;
      }
    }
    __syncthreads();
    #pragma unroll 8
    for (int k=0;k<192;k++){
      float w = w_s[j*193+k];
      float4 a = *reinterpret_cast<const float4*>(&a_lds[k*20 + rg*4]);
      acc[0]+=a.x*w; acc[1]+=a.y*w; acc[2]+=a.z*w; acc[3]+=a.w*w;
    }
  }
  #pragma unroll
  for (int q=0;q<4;q++){
    int row = r0 + rg*4 + q;
    if (row<NROW) residual[(size_t)row*DMODEL + c0 + j] += acc[q];
  }
}

// final RMSNorm -> d_out
__global__ __launch_bounds__(256) void k_final(const float* __restrict__ residual,
    const float* __restrict__ nfw, float* __restrict__ out){
  int wv = threadIdx.x>>6, lane = threadIdx.x&63;
  int row = blockIdx.x*4 + wv;
  if (row >= NROW) return;
  float v[3]; float s = 0.f;
  #pragma unroll
  for (int q=0;q<3;q++){ v[q] = residual[(size_t)row*DMODEL + lane + q*64]; s += v[q]*v[q]; }
  #pragma unroll
  for (int off=1; off<64; off<<=1) s += __shfl_xor(s, off, 64);
  float sc = rsqrtf(s/(float)DMODEL + EPSF);
  #pragma unroll
  for (int q=0;q<3;q++) out[(size_t)row*DMODEL + lane + q*64] = v[q]*sc*nfw[lane + q*64];
}

// ---------------- host ----------------
extern "C" void kernel_launch(void* const* d_in, const int* in_sizes, int n_in,
                              void* d_out, int out_size, void* d_ws, size_t ws_size,
                              hipStream_t stream){
  const float* tokens     = (const float*)d_in[0];
  const float* norm_w     = (const float*)d_in[1];
  const float* in_proj_w  = (const float*)d_in[2];
  const float* conv_w     = (const float*)d_in[3];
  const float* conv_b     = (const float*)d_in[4];
  const float* conv_w_b   = (const float*)d_in[5];
  const float* conv_b_b   = (const float*)d_in[6];
  const float* x_proj_w   = (const float*)d_in[7];
  const float* x_proj_w_b = (const float*)d_in[8];
  const float* dt_proj_w  = (const float*)d_in[9];
  const float* dt_bias    = (const float*)d_in[10];
  const float* dt_proj_w_b= (const float*)d_in[11];
  const float* dt_bias_b  = (const float*)d_in[12];
  const float* A_log      = (const float*)d_in[13];
  const float* A_log_b    = (const float*)d_in[14];
  const float* D_param    = (const float*)d_in[15];
  const float* D_param_b  = (const float*)d_in[16];
  const float* out_proj_w = (const float*)d_in[17];
  const float* norm_f_w   = (const float*)d_in[18];

  float* ws = (float*)d_ws;
  size_t off = 0;
  float* residual = ws + off; off += (size_t)NROW*DMODEL;
  float* xn       = ws + off; off += (size_t)NROW*DMODEL;
  float* xz       = ws + off; off += (size_t)NROW*768;
  float* xf_f     = ws + off; off += (size_t)NROW*DINNER;
  float* xf_b     = ws + off; off += (size_t)NROW*DINNER;
  float* dtbc_f   = ws + off; off += (size_t)NROW*44;
  float* dtbc_b   = ws + off; off += (size_t)NROW*44;
  float* dt_f     = ws + off; off += (size_t)NROW*DINNER;
  float* dt_b     = ws + off; off += (size_t)NROW*DINNER;
  float* y_f      = ws + off; off += (size_t)NROW*DINNER;
  float* y_b      = ws + off; off += (size_t)NROW*DINNER;
  float* gbuf     = ws + off; off += (size_t)NROW*DINNER;
  float* q_buf    = ws + off; off += (size_t)2*BB*NCH2*DINNER*DSTATE;
  float* sdt_buf  = ws + off; off += (size_t)2*BB*NCH2*DINNER;
  float* AnTF     = ws + off; off += (size_t)NLAYER*DINNER*DSTATE;
  float* AnTB     = ws + off; off += (size_t)NLAYER*DINNER*DSTATE;
  if (off*sizeof(float) > ws_size) return;   // workspace too small: fail loudly

  // prep (3 dispatches; no weight transposes needed — GEMMs consume native layout)
  k_init<<<dim3((NROW*DMODEL+255)/256),256,0,stream>>>(tokens, residual, NROW*DMODEL);
  k_negexpT2<<<dim3((NLAYER*DINNER*DSTATE+255)/256),256,0,stream>>>(A_log,   AnTF, NLAYER*DINNER*DSTATE);
  k_negexpT2<<<dim3((NLAYER*DINNER*DSTATE+255)/256),256,0,stream>>>(A_log_b, AnTB, NLAYER*DINNER*DSTATE);

  const int RT16 = (NROW+15)/16;              // 103
  const int EW4  = (NROW*(DINNER/4)+255)/256; // 614
  for (int l=0; l<NLAYER; l++){
    k_prenorm<<<dim3((NROW+3)/4),256,0,stream>>>(residual, norm_w + (size_t)l*DMODEL, xn);
    k_gemm_in<<<dim3(RT16,12),256,0,stream>>>(xn, in_proj_w + (size_t)l*768*DMODEL, xz);
    k_conv<<<dim3(EW4,2),256,0,stream>>>(xz,
        conv_w + (size_t)l*DINNER*KCONV, conv_b + (size_t)l*DINNER,
        conv_w_b + (size_t)l*DINNER*KCONV, conv_b_b + (size_t)l*DINNER, xf_f, xf_b);
    k_xp2<<<dim3(RT16,1,2),256,0,stream>>>(xf_f, xf_b,
        x_proj_w + (size_t)l*44*DINNER, x_proj_w_b + (size_t)l*44*DINNER,
        dt_proj_w + (size_t)l*DINNER*DRANK, dt_proj_w_b + (size_t)l*DINNER*DRANK,
        dt_bias + (size_t)l*DINNER, dt_bias_b + (size_t)l*DINNER,
        dtbc_f, dtbc_b, dt_f, dt_b);
    k_scan1<<<dim3(3,BB*NCH2,2),128,0,stream>>>(xf_f, xf_b, dtbc_f, dtbc_b, dt_f, dt_b,
        AnTF + (size_t)l*DINNER*DSTATE, AnTB + (size_t)l*DINNER*DSTATE, q_buf, sdt_buf);
    k_scan2<<<dim3(3,BB*NCH2,2),128,0,stream>>>(xf_f, xf_b, dtbc_f, dtbc_b, dt_f, dt_b,
        AnTF + (size_t)l*DINNER*DSTATE, AnTB + (size_t)l*DINNER*DSTATE,
        D_param + (size_t)l*DINNER, D_param_b + (size_t)l*DINNER,
        q_buf, sdt_buf, y_f, y_b);
    k_gate<<<dim3(EW4),256,0,stream>>>(y_f, y_b, xz, gbuf);
    k_gemm_out<<<dim3(RT16,3),256,0,stream>>>(gbuf, out_proj_w + (size_t)l*DMODEL*DINNER, residual);
  }
  k_final<<<dim3((NROW+3)/4),256,0,stream>>>(residual, norm_f_w, (float*)d_out);
}

// Round 11
// 2387.715 us; speedup vs baseline: 1.0271x; 1.0271x over previous
//
#include <hip/hip_runtime.h>
#include <math.h>

#define BB     4
#define LLEN   409
#define DMODEL 192
#define DINNER 384
#define DSTATE 16
#define DRANK  12
#define KCONV  4
#define NLAYER 24
#define NROW   (BB*LLEN)      /* 1636 */
#define EPSF   1e-5f
#define CH2    16             /* scan chunk length */
#define NCH2   26             /* 16*26=416 >= 409 */

__device__ __forceinline__ float siluf(float x){ return x/(1.f+__expf(-x)); }
__device__ __forceinline__ float softplusf(float x){ return (x>20.f)? x : log1pf(__expf(x)); }

// ---------------- prep kernels ----------------
// fused: residual init + AnT (both dirs). AnT[l][n][d] = -exp(A_log[l][d][n])
__global__ void k_prep(const float* __restrict__ tokens, float* __restrict__ residual,
    const float* __restrict__ alF, const float* __restrict__ alB,
    float* __restrict__ anF, float* __restrict__ anB){
  int i = blockIdx.x*256+threadIdx.x;
  if (i < NROW*DMODEL) residual[i] = tokens[i];
  if (i < NLAYER*DINNER*DSTATE){
    int l = i/(DINNER*DSTATE); int rem = i%(DINNER*DSTATE);
    int nn = rem/DINNER, d = rem%DINNER;
    size_t src = ((size_t)l*DINNER + d)*DSTATE + nn;
    anF[i] = -expf(alF[src]);
    anB[i] = -expf(alB[src]);
  }
}

// tiled transpose: src [L][R][C] -> dst [L][C][RP] (rows r>=R in dst are zero)
// grid (ceil(C/32), ceil(RP/32), NLAYER), block (32,8)
__global__ __launch_bounds__(256) void k_txp(const float* __restrict__ src,
    float* __restrict__ dst, int R, int C, int RP){
  __shared__ float t[32][33];
  int l = blockIdx.z;
  int c0 = blockIdx.x*32, r0 = blockIdx.y*32;
  const float* s = src + (size_t)l*R*C;
  float* d = dst + (size_t)l*C*RP;
  int tx = threadIdx.x, ty = threadIdx.y;
  #pragma unroll
  for (int yy=ty; yy<32; yy+=8){
    int rr = r0+yy, cc = c0+tx;
    t[yy][tx] = (rr<R && cc<C)? s[(size_t)rr*C+cc] : 0.f;
  }
  __syncthreads();
  #pragma unroll
  for (int yy=ty; yy<32; yy+=8){
    int cc = c0+yy, rr = r0+tx;
    if (cc<C && rr<RP) d[(size_t)cc*RP+rr] = t[tx][yy];
  }
}

// ---------------- layer kernels ----------------
// RMSNorm: xn = residual * rsqrt(mean sq) * norm_w; one wave per row
__global__ __launch_bounds__(256) void k_prenorm(const float* __restrict__ residual,
    const float* __restrict__ norm_w, float* __restrict__ xn){
  int wv = threadIdx.x>>6, lane = threadIdx.x&63;
  int row = blockIdx.x*4 + wv;
  if (row >= NROW) return;
  float v[3]; float s = 0.f;
  #pragma unroll
  for (int q=0;q<3;q++){ v[q] = residual[(size_t)row*DMODEL + lane + q*64]; s += v[q]*v[q]; }
  #pragma unroll
  for (int off=1; off<64; off<<=1) s += __shfl_xor(s, off, 64);
  float sc = rsqrtf(s/(float)DMODEL + EPSF);
  #pragma unroll
  for (int q=0;q<3;q++) xn[(size_t)row*DMODEL + lane + q*64] = v[q]*sc*norm_w[lane + q*64];
}

// in_proj GEMM: xz[NROW][768] = xn[NROW][192] @ WtIn[192][768]; BM=16 BN=64; grid (103,12)
__global__ __launch_bounds__(256) void k_gemm_in(const float* __restrict__ xn,
    const float* __restrict__ Wt, float* __restrict__ xz){
  __shared__ __align__(16) float w_lds[192*64];
  __shared__ __align__(16) float a_lds[192*20];
  int tid = threadIdx.x, r0 = blockIdx.x*16, c0 = blockIdx.y*64;
  {
    int j4 = (tid&15)*4, kr = tid>>4;
    #pragma unroll
    for (int s=0;s<12;s++){
      int k = kr + s*16;
      *reinterpret_cast<float4*>(&w_lds[k*64+j4]) =
        *reinterpret_cast<const float4*>(&Wt[(size_t)k*768 + c0 + j4]);
    }
  }
  {
    int i = tid>>4, kc = (tid&15)*12;
    int row = r0+i;
    #pragma unroll
    for (int m=0;m<12;m+=4){
      float4 v = make_float4(0.f,0.f,0.f,0.f);
      if (row<NROW) v = *reinterpret_cast<const float4*>(&xn[(size_t)row*192 + kc + m]);
      a_lds[(kc+m+0)*20+i]=v.x; a_lds[(kc+m+1)*20+i]=v.y;
      a_lds[(kc+m+2)*20+i]=v.z; a_lds[(kc+m+3)*20+i]=v.w;
    }
  }
  __syncthreads();
  int j = tid & 63, rg = tid >> 6;
  float acc[4] = {0.f,0.f,0.f,0.f};
  #pragma unroll 8
  for (int k=0;k<192;k++){
    float w = w_lds[k*64+j];
    float4 a = *reinterpret_cast<const float4*>(&a_lds[k*20 + rg*4]);
    acc[0]+=a.x*w; acc[1]+=a.y*w; acc[2]+=a.z*w; acc[3]+=a.w*w;
  }
  #pragma unroll
  for (int q=0;q<4;q++){
    int row = r0 + rg*4 + q;
    if (row<NROW) xz[(size_t)row*768 + c0 + j] = acc[q];
  }
}

// causal depthwise conv + bias + silu, float4 over d; grid (614, 2)
__global__ __launch_bounds__(256) void k_conv(const float* __restrict__ xz,
    const float* __restrict__ cwf, const float* __restrict__ cbf,
    const float* __restrict__ cwb, const float* __restrict__ cbb,
    float* __restrict__ xf_f, float* __restrict__ xf_b){
  int idx = blockIdx.x*256 + threadIdx.x;
  if (idx >= NROW*(DINNER/4)) return;
  int d4 = (idx % (DINNER/4))*4; int bl = idx / (DINNER/4);
  int b = bl / LLEN; int l = bl % LLEN;
  int dir = blockIdx.y;
  const float* cw = dir? cwb : cwf;
  const float* cb = dir? cbb : cbf;
  float4 w0 = *reinterpret_cast<const float4*>(&cw[(d4+0)*KCONV]);
  float4 w1 = *reinterpret_cast<const float4*>(&cw[(d4+1)*KCONV]);
  float4 w2 = *reinterpret_cast<const float4*>(&cw[(d4+2)*KCONV]);
  float4 w3 = *reinterpret_cast<const float4*>(&cw[(d4+3)*KCONV]);
  float4 acc = *reinterpret_cast<const float4*>(&cb[d4]);
  const float* wa0 = (const float*)&w0; const float* wa1 = (const float*)&w1;
  const float* wa2 = (const float*)&w2; const float* wa3 = (const float*)&w3;
  #pragma unroll
  for (int k=0;k<KCONV;k++){
    int o = dir? (LLEN-1-l-k+3) : (l-3+k);
    bool ok = dir? (l+k>=3) : (o>=0);
    if (ok){
      float4 x = *reinterpret_cast<const float4*>(&xz[((size_t)(b*LLEN+o))*768 + d4]);
      acc.x += wa0[k]*x.x; acc.y += wa1[k]*x.y; acc.z += wa2[k]*x.z; acc.w += wa3[k]*x.w;
    }
  }
  float* out = dir? xf_b : xf_f;
  float4 r; r.x = siluf(acc.x); r.y = siluf(acc.y); r.z = siluf(acc.z); r.w = siluf(acc.w);
  *reinterpret_cast<float4*>(&out[(size_t)bl*DINNER + d4]) = r;
}

// x_proj (padded to 64 cols) + dt_proj + softplus; BM=16; grid (103,1,2)
__global__ __launch_bounds__(256) void k_xp2(
    const float* __restrict__ xf_f, const float* __restrict__ xf_b,
    const float* __restrict__ WxpPF, const float* __restrict__ WxpPB,  // [384][64]
    const float* __restrict__ WdtF, const float* __restrict__ WdtB,    // [12][384]
    const float* __restrict__ dtbF, const float* __restrict__ dtbB,
    float* __restrict__ dtbc_f, float* __restrict__ dtbc_b,
    float* __restrict__ dt_f, float* __restrict__ dt_b){
  __shared__ __align__(16) float w_lds[192*64];
  __shared__ __align__(16) float a_lds[192*20];
  __shared__ float dtin_s[16*12];
  int dir = blockIdx.z;
  const float* xf  = dir? xf_b : xf_f;
  const float* Wxp = dir? WxpPB : WxpPF;
  const float* Wdt = dir? WdtB : WdtF;
  const float* dtb = dir? dtbB : dtbF;
  float* dtbc = dir? dtbc_b : dtbc_f;
  float* dtp  = dir? dt_b  : dt_f;
  int tid = threadIdx.x, r0 = blockIdx.x*16;
  int j = tid & 63, rg = tid >> 6;
  float acc[4] = {0.f,0.f,0.f,0.f};
  for (int c=0;c<2;c++){
    int K0 = c*192;
    if (c) __syncthreads();
    {
      int j4 = (tid&15)*4, kr = tid>>4;
      #pragma unroll
      for (int s=0;s<12;s++){
        int k = kr + s*16;
        *reinterpret_cast<float4*>(&w_lds[k*64+j4]) =
          *reinterpret_cast<const float4*>(&Wxp[(size_t)(K0+k)*64 + j4]);
      }
    }
    {
      int i = tid>>4, kc = (tid&15)*12;
      int row = r0+i;
      #pragma unroll
      for (int m=0;m<12;m+=4){
        float4 v = make_float4(0.f,0.f,0.f,0.f);
        if (row<NROW) v = *reinterpret_cast<const float4*>(&xf[(size_t)row*DINNER + K0 + kc + m]);
        a_lds[(kc+m+0)*20+i]=v.x; a_lds[(kc+m+1)*20+i]=v.y;
        a_lds[(kc+m+2)*20+i]=v.z; a_lds[(kc+m+3)*20+i]=v.w;
      }
    }
    __syncthreads();
    #pragma unroll 8
    for (int k=0;k<192;k++){
      float w = w_lds[k*64+j];
      float4 a = *reinterpret_cast<const float4*>(&a_lds[k*20 + rg*4]);
      acc[0]+=a.x*w; acc[1]+=a.y*w; acc[2]+=a.z*w; acc[3]+=a.w*w;
    }
  }
  __syncthreads();
  #pragma unroll
  for (int q=0;q<4;q++){
    int i = rg*4+q, row = r0+i;
    if (j<44 && row<NROW) dtbc[(size_t)row*44 + j] = acc[q];
    if (j<12) dtin_s[i*12 + j] = acc[q];
  }
  __syncthreads();
  for (int idx=tid; idx<12*DINNER; idx+=256) w_lds[idx] = Wdt[idx];
  __syncthreads();
  for (int idx=tid; idx<16*DINNER; idx+=256){
    int i = idx/DINNER, dd = idx - i*DINNER;
    int row = r0+i;
    float v = dtb[dd];
    #pragma unroll
    for (int r=0;r<12;r++) v += dtin_s[i*12+r]*w_lds[r*DINNER+dd];
    if (row<NROW) dtp[(size_t)row*DINNER+dd] = softplusf(v);
  }
}

// scan pass 1: per-chunk transfer fn; thread = one d, 16 n-states in regs
// grid (3, BB*NCH2, 2), 128 threads
__global__ __launch_bounds__(128) void k_scan1(
    const float* __restrict__ xf_f, const float* __restrict__ xf_b,
    const float* __restrict__ dtbc_f, const float* __restrict__ dtbc_b,
    const float* __restrict__ dt_f, const float* __restrict__ dt_b,
    const float* __restrict__ anF, const float* __restrict__ anB,
    float* __restrict__ q_buf, float* __restrict__ sdt_buf){
  int dir = blockIdx.z;
  int b  = blockIdx.y / NCH2;
  int ch = blockIdx.y % NCH2;
  if (ch == NCH2-1) return;   // last chunk's transfer fn is never consumed
  const float* xf   = dir? xf_b  : xf_f;
  const float* dtbc = dir? dtbc_b: dtbc_f;
  const float* dtp  = dir? dt_b  : dt_f;
  const float* an   = dir? anB   : anF;
  int t0 = ch*CH2;
  int T  = CH2;               // ch < NCH2-1 -> always full
  int d0 = blockIdx.x*128;
  size_t base = (size_t)b*LLEN + t0;
  __shared__ float dt_s[CH2*128], u_s[CH2*128];
  __shared__ __align__(16) float B_s[CH2*16];
  int tid = threadIdx.x;
  for (int t=0;t<T;t++){
    dt_s[t*128+tid] = dtp[(base+t)*DINNER + d0 + tid];
    u_s [t*128+tid] = xf [(base+t)*DINNER + d0 + tid];
  }
  for (int idx = tid; idx < T*16; idx += 128){
    int t = idx>>4, n = idx&15;
    B_s[idx] = dtbc[(base+t)*44 + 12 + n];
  }
  __syncthreads();
  int d = d0 + tid;
  float A[16], h[16];
  #pragma unroll
  for (int n=0;n<16;n++){ A[n] = an[n*DINNER + d]; h[n] = 0.f; }
  float sdt = 0.f;
  for (int t=0;t<T;t++){
    float dtv = dt_s[t*128+tid];
    float du  = dtv * u_s[t*128+tid];
    float Bv[16];
    #pragma unroll
    for (int q=0;q<4;q++) *reinterpret_cast<float4*>(&Bv[q*4]) =
        *reinterpret_cast<const float4*>(&B_s[t*16 + q*4]);
    #pragma unroll
    for (int n=0;n<16;n++) h[n] = h[n]*__expf(dtv*A[n]) + du*Bv[n];
    sdt += dtv;
  }
  size_t ci = ((size_t)dir*BB + b)*NCH2 + ch;
  float* qo = &q_buf[(ci*DINNER + d)*DSTATE];
  #pragma unroll
  for (int q=0;q<4;q++) *reinterpret_cast<float4*>(&qo[q*4]) =
      make_float4(h[q*4+0], h[q*4+1], h[q*4+2], h[q*4+3]);
  sdt_buf[ci*DINNER + d] = sdt;
}

// scan pass 2: fold carries of preceding chunks in-thread, replay chunk, emit y
// grid (3, BB*NCH2, 2), 128 threads
__global__ __launch_bounds__(128) void k_scan2(
    const float* __restrict__ xf_f, const float* __restrict__ xf_b,
    const float* __restrict__ dtbc_f, const float* __restrict__ dtbc_b,
    const float* __restrict__ dt_f, const float* __restrict__ dt_b,
    const float* __restrict__ anF, const float* __restrict__ anB,
    const float* __restrict__ DpF, const float* __restrict__ DpB,
    const float* __restrict__ q_buf, const float* __restrict__ sdt_buf,
    float* __restrict__ y_fo, float* __restrict__ y_bo){
  int dir = blockIdx.z;
  int b  = blockIdx.y / NCH2;
  int ch = blockIdx.y % NCH2;
  const float* xf   = dir? xf_b  : xf_f;
  const float* dtbc = dir? dtbc_b: dtbc_f;
  const float* dtp  = dir? dt_b  : dt_f;
  const float* an   = dir? anB   : anF;
  const float* Dp   = dir? DpB   : DpF;
  float* y = dir? y_bo : y_fo;
  int t0 = ch*CH2;
  int T  = (t0+CH2<=LLEN)? CH2 : (LLEN-t0);
  int d0 = blockIdx.x*128;
  size_t base = (size_t)b*LLEN + t0;
  __shared__ float dt_s[CH2*128], u_s[CH2*128];
  __shared__ __align__(16) float B_s[CH2*16], C_s[CH2*16];
  int tid = threadIdx.x;
  for (int t=0;t<T;t++){
    dt_s[t*128+tid] = dtp[(base+t)*DINNER + d0 + tid];
    u_s [t*128+tid] = xf [(base+t)*DINNER + d0 + tid];
  }
  for (int idx = tid; idx < T*16; idx += 128){
    int t = idx>>4, n = idx&15;
    B_s[idx] = dtbc[(base+t)*44 + 12 + n];
    C_s[idx] = dtbc[(base+t)*44 + 28 + n];
  }
  __syncthreads();
  int d = d0 + tid;
  float A[16], h[16];
  #pragma unroll
  for (int n=0;n<16;n++){ A[n] = an[n*DINNER + d]; h[n] = 0.f; }
  // fold transfer functions of preceding chunks: h <- q_cc + exp(A*sdt_cc)*h
  size_t sbase = ((size_t)dir*BB + b)*NCH2;
  for (int cc=0; cc<ch; cc++){
    float sv = sdt_buf[(sbase+cc)*DINNER + d];
    const float* qp = &q_buf[((sbase+cc)*DINNER + d)*DSTATE];
    float qv[16];
    #pragma unroll
    for (int q=0;q<4;q++) *reinterpret_cast<float4*>(&qv[q*4]) =
        *reinterpret_cast<const float4*>(&qp[q*4]);
    #pragma unroll
    for (int n=0;n<16;n++) h[n] = qv[n] + __expf(A[n]*sv)*h[n];
  }
  float Dd = Dp[d];
  for (int t=0;t<T;t++){
    float dtv = dt_s[t*128+tid];
    float u   = u_s [t*128+tid];
    float du  = dtv*u;
    float Bv[16], Cv[16];
    #pragma unroll
    for (int q=0;q<4;q++){
      *reinterpret_cast<float4*>(&Bv[q*4]) = *reinterpret_cast<const float4*>(&B_s[t*16+q*4]);
      *reinterpret_cast<float4*>(&Cv[q*4]) = *reinterpret_cast<const float4*>(&C_s[t*16+q*4]);
    }
    float y0=0.f, y1=0.f, y2=0.f, y3=0.f;
    #pragma unroll
    for (int n=0;n<16;n+=4){
      h[n+0] = h[n+0]*__expf(dtv*A[n+0]) + du*Bv[n+0];
      h[n+1] = h[n+1]*__expf(dtv*A[n+1]) + du*Bv[n+1];
      h[n+2] = h[n+2]*__expf(dtv*A[n+2]) + du*Bv[n+2];
      h[n+3] = h[n+3]*__expf(dtv*A[n+3]) + du*Bv[n+3];
      y0 += h[n+0]*Cv[n+0]; y1 += h[n+1]*Cv[n+1];
      y2 += h[n+2]*Cv[n+2]; y3 += h[n+3]*Cv[n+3];
    }
    y[(base+t)*DINNER + d] = (y0+y1)+(y2+y3) + u*Dd;
  }
}

// gate: g = (y_f + y_b(reversed)) * silu(z) * 0.5; grid (614)
__global__ __launch_bounds__(256) void k_gate(
    const float* __restrict__ y_f, const float* __restrict__ y_b,
    const float* __restrict__ xz, float* __restrict__ g){
  int idx = blockIdx.x*256 + threadIdx.x;
  if (idx >= NROW*(DINNER/4)) return;
  int d4 = (idx % (DINNER/4))*4; int row = idx / (DINNER/4);
  int b = row/LLEN, l = row%LLEN;
  int rrow = b*LLEN + (LLEN-1-l);
  float4 yf = *reinterpret_cast<const float4*>(&y_f[(size_t)row*DINNER + d4]);
  float4 yb = *reinterpret_cast<const float4*>(&y_b[(size_t)rrow*DINNER + d4]);
  float4 z  = *reinterpret_cast<const float4*>(&xz[(size_t)row*768 + DINNER + d4]);
  float4 r;
  r.x = (yf.x+yb.x)*siluf(z.x)*0.5f; r.y = (yf.y+yb.y)*siluf(z.y)*0.5f;
  r.z = (yf.z+yb.z)*siluf(z.z)*0.5f; r.w = (yf.w+yb.w)*siluf(z.w)*0.5f;
  *reinterpret_cast<float4*>(&g[(size_t)row*DINNER + d4]) = r;
}

// out_proj GEMM: residual += g[NROW][384] @ WtOut[384][192]; BM=16 BN=64; grid (103,3)
__global__ __launch_bounds__(256) void k_gemm_out(const float* __restrict__ g,
    const float* __restrict__ Wt, float* __restrict__ residual){
  __shared__ __align__(16) float w_lds[192*64];
  __shared__ __align__(16) float a_lds[192*20];
  int tid = threadIdx.x, r0 = blockIdx.x*16, c0 = blockIdx.y*64;
  int j = tid & 63, rg = tid >> 6;
  float acc[4] = {0.f,0.f,0.f,0.f};
  for (int c=0;c<2;c++){
    int K0 = c*192;
    if (c) __syncthreads();
    {
      int j4 = (tid&15)*4, kr = tid>>4;
      #pragma unroll
      for (int s=0;s<12;s++){
        int k = kr + s*16;
        *reinterpret_cast<float4*>(&w_lds[k*64+j4]) =
          *reinterpret_cast<const float4*>(&Wt[(size_t)(K0+k)*192 + c0 + j4]);
      }
    }
    {
      int i = tid>>4, kc = (tid&15)*12;
      int row = r0+i;
      #pragma unroll
      for (int m=0;m<12;m+=4){
        float4 v = make_float4(0.f,0.f,0.f,0.f);
        if (row<NROW) v = *reinterpret_cast<const float4*>(&g[(size_t)row*DINNER + K0 + kc + m]);
        a_lds[(kc+m+0)*20+i]=v.x; a_lds[(kc+m+1)*20+i]=v.y;
        a_lds[(kc+m+2)*20+i]=v.z; a_lds[(kc+m+3)*20+i]=v.w;
      }
    }
    __syncthreads();
    #pragma unroll 8
    for (int k=0;k<192;k++){
      float w = w_lds[k*64+j];
      float4 a = *reinterpret_cast<const float4*>(&a_lds[k*20 + rg*4]);
      acc[0]+=a.x*w; acc[1]+=a.y*w; acc[2]+=a.z*w; acc[3]+=a.w*w;
    }
  }
  #pragma unroll
  for (int q=0;q<4;q++){
    int row = r0 + rg*4 + q;
    if (row<NROW) residual[(size_t)row*DMODEL + c0 + j] += acc[q];
  }
}

// final RMSNorm -> d_out
__global__ __launch_bounds__(256) void k_final(const float* __restrict__ residual,
    const float* __restrict__ nfw, float* __restrict__ out){
  int wv = threadIdx.x>>6, lane = threadIdx.x&63;
  int row = blockIdx.x*4 + wv;
  if (row >= NROW) return;
  float v[3]; float s = 0.f;
  #pragma unroll
  for (int q=0;q<3;q++){ v[q] = residual[(size_t)row*DMODEL + lane + q*64]; s += v[q]*v[q]; }
  #pragma unroll
  for (int off=1; off<64; off<<=1) s += __shfl_xor(s, off, 64);
  float sc = rsqrtf(s/(float)DMODEL + EPSF);
  #pragma unroll
  for (int q=0;q<3;q++) out[(size_t)row*DMODEL + lane + q*64] = v[q]*sc*nfw[lane + q*64];
}

// ---------------- host ----------------
extern "C" void kernel_launch(void* const* d_in, const int* in_sizes, int n_in,
                              void* d_out, int out_size, void* d_ws, size_t ws_size,
                              hipStream_t stream){
  const float* tokens     = (const float*)d_in[0];
  const float* norm_w     = (const float*)d_in[1];
  const float* in_proj_w  = (const float*)d_in[2];
  const float* conv_w     = (const float*)d_in[3];
  const float* conv_b     = (const float*)d_in[4];
  const float* conv_w_b   = (const float*)d_in[5];
  const float* conv_b_b   = (const float*)d_in[6];
  const float* x_proj_w   = (const float*)d_in[7];
  const float* x_proj_w_b = (const float*)d_in[8];
  const float* dt_proj_w  = (const float*)d_in[9];
  const float* dt_bias    = (const float*)d_in[10];
  const float* dt_proj_w_b= (const float*)d_in[11];
  const float* dt_bias_b  = (const float*)d_in[12];
  const float* A_log      = (const float*)d_in[13];
  const float* A_log_b    = (const float*)d_in[14];
  const float* D_param    = (const float*)d_in[15];
  const float* D_param_b  = (const float*)d_in[16];
  const float* out_proj_w = (const float*)d_in[17];
  const float* norm_f_w   = (const float*)d_in[18];

  float* ws = (float*)d_ws;
  size_t off = 0;
  float* residual = ws + off; off += (size_t)NROW*DMODEL;
  float* xn       = ws + off; off += (size_t)NROW*DMODEL;
  float* xz       = ws + off; off += (size_t)NROW*768;
  float* xf_f     = ws + off; off += (size_t)NROW*DINNER;
  float* xf_b     = ws + off; off += (size_t)NROW*DINNER;
  float* dtbc_f   = ws + off; off += (size_t)NROW*44;
  float* dtbc_b   = ws + off; off += (size_t)NROW*44;
  float* dt_f     = ws + off; off += (size_t)NROW*DINNER;
  float* dt_b     = ws + off; off += (size_t)NROW*DINNER;
  float* y_f      = ws + off; off += (size_t)NROW*DINNER;
  float* y_b      = ws + off; off += (size_t)NROW*DINNER;
  float* gbuf     = ws + off; off += (size_t)NROW*DINNER;
  float* q_buf    = ws + off; off += (size_t)2*BB*NCH2*DINNER*DSTATE;
  float* sdt_buf  = ws + off; off += (size_t)2*BB*NCH2*DINNER;
  float* WtIn     = ws + off; off += (size_t)NLAYER*DMODEL*768;
  float* WtXpPF   = ws + off; off += (size_t)NLAYER*DINNER*64;
  float* WtXpPB   = ws + off; off += (size_t)NLAYER*DINNER*64;
  float* WtDtF    = ws + off; off += (size_t)NLAYER*DRANK*DINNER;
  float* WtDtB    = ws + off; off += (size_t)NLAYER*DRANK*DINNER;
  float* WtOut    = ws + off; off += (size_t)NLAYER*DINNER*DMODEL;
  float* AnTF     = ws + off; off += (size_t)NLAYER*DINNER*DSTATE;
  float* AnTB     = ws + off; off += (size_t)NLAYER*DINNER*DSTATE;
  if (off*sizeof(float) > ws_size) return;   // workspace too small: fail loudly

  // prep (all coalesced, tiled)
  k_prep<<<dim3((NROW*DMODEL+255)/256),256,0,stream>>>(tokens, residual, A_log, A_log_b, AnTF, AnTB);
  dim3 tb(32,8);
  k_txp<<<dim3(6,24,NLAYER),tb,0,stream>>>(in_proj_w,  WtIn,   768, 192, 768);
  k_txp<<<dim3(12,2,NLAYER),tb,0,stream>>>(x_proj_w,   WtXpPF,  44, 384,  64);
  k_txp<<<dim3(12,2,NLAYER),tb,0,stream>>>(x_proj_w_b, WtXpPB,  44, 384,  64);
  k_txp<<<dim3(1,12,NLAYER),tb,0,stream>>>(dt_proj_w,  WtDtF,  384,  12, 384);
  k_txp<<<dim3(1,12,NLAYER),tb,0,stream>>>(dt_proj_w_b,WtDtB,  384,  12, 384);
  k_txp<<<dim3(12,6,NLAYER),tb,0,stream>>>(out_proj_w, WtOut,  192, 384, 192);

  const int RT16 = (NROW+15)/16;              // 103
  const int EW4  = (NROW*(DINNER/4)+255)/256; // 614
  for (int l=0; l<NLAYER; l++){
    k_prenorm<<<dim3((NROW+3)/4),256,0,stream>>>(residual, norm_w + (size_t)l*DMODEL, xn);
    k_gemm_in<<<dim3(RT16,12),256,0,stream>>>(xn, WtIn + (size_t)l*DMODEL*768, xz);
    k_conv<<<dim3(EW4,2),256,0,stream>>>(xz,
        conv_w + (size_t)l*DINNER*KCONV, conv_b + (size_t)l*DINNER,
        conv_w_b + (size_t)l*DINNER*KCONV, conv_b_b + (size_t)l*DINNER, xf_f, xf_b);
    k_xp2<<<dim3(RT16,1,2),256,0,stream>>>(xf_f, xf_b,
        WtXpPF + (size_t)l*DINNER*64, WtXpPB + (size_t)l*DINNER*64,
        WtDtF + (size_t)l*DRANK*DINNER, WtDtB + (size_t)l*DRANK*DINNER,
        dt_bias + (size_t)l*DINNER, dt_bias_b + (size_t)l*DINNER,
        dtbc_f, dtbc_b, dt_f, dt_b);
    k_scan1<<<dim3(3,BB*NCH2,2),128,0,stream>>>(xf_f, xf_b, dtbc_f, dtbc_b, dt_f, dt_b,
        AnTF + (size_t)l*DINNER*DSTATE, AnTB + (size_t)l*DINNER*DSTATE, q_buf, sdt_buf);
    k_scan2<<<dim3(3,BB*NCH2,2),128,0,stream>>>(xf_f, xf_b, dtbc_f, dtbc_b, dt_f, dt_b,
        AnTF + (size_t)l*DINNER*DSTATE, AnTB + (size_t)l*DINNER*DSTATE,
        D_param + (size_t)l*DINNER, D_param_b + (size_t)l*DINNER,
        q_buf, sdt_buf, y_f, y_b);
    k_gate<<<dim3(EW4),256,0,stream>>>(y_f, y_b, xz, gbuf);
    k_gemm_out<<<dim3(RT16,3),256,0,stream>>>(gbuf, WtOut + (size_t)l*DINNER*DMODEL, residual);
  }
  k_final<<<dim3((NROW+3)/4),256,0,stream>>>(residual, norm_f_w, (float*)d_out);
}